// Round 17
// baseline (67.746 us; speedup 1.0000x reference)
//
#include <hip/hip_runtime.h>

#define TT 2048
#define LL 288
#define CC 1024
#define SLOTB2 74752  // 128-row partial: m[128]f32 + l[128]f32 + O-blob [9][512][16B] bf16

typedef __attribute__((ext_vector_type(8))) short bf16x8;
typedef __attribute__((ext_vector_type(4))) float f32x4;
typedef __attribute__((ext_vector_type(4))) unsigned int u32x4;
typedef __attribute__((ext_vector_type(2))) unsigned int u32x2;
typedef __attribute__((ext_vector_type(4))) short s16x4;

__device__ __forceinline__ unsigned short f2bf(float f) {
  unsigned u = __float_as_uint(f);
  u += 0x7fffu + ((u >> 16) & 1u);
  return (unsigned short)(u >> 16);
}

__device__ __forceinline__ u32x2 pack4(f32x4 v) {
  u32x2 p;
  p.x = (unsigned)f2bf(v.x) | ((unsigned)f2bf(v.y) << 16);
  p.y = (unsigned)f2bf(v.z) | ((unsigned)f2bf(v.w) << 16);
  return p;
}

__device__ __forceinline__ f32x4 mfma16(bf16x8 a, bf16x8 b, f32x4 c) {
  return __builtin_amdgcn_mfma_f32_16x16x32_bf16(a, b, c, 0, 0, 0);
}

__device__ __forceinline__ bf16x8 as_bf(u32x4 u) {
  return __builtin_bit_cast(bf16x8, u);
}

// packed bf16 convert: dword = {bf16(lo) | bf16(hi)<<16}
__device__ __forceinline__ unsigned cvtpk(float lo, float hi) {
  unsigned d;
  asm("v_cvt_pk_bf16_f32 %0, %1, %2" : "=v"(d) : "v"(lo), "v"(hi));
  return d;
}

typedef __attribute__((address_space(3))) const unsigned short* lds_cptr;
typedef __attribute__((address_space(1))) const void* gvp;
typedef __attribute__((address_space(3))) void* svp;

// ds_read_b64_tr_b16: lane fetches 8B at its own addr (subtile base + (lane&15)*8);
// HW transposes within 16-lane groups: lane c elem j holds tile[j][c] of [4][16] bf16.
__device__ __forceinline__ s16x4 tr16(const void* p) {
  s16x4 r;
  lds_cptr lp = (lds_cptr)p;
  asm volatile("ds_read_b64_tr_b16 %0, %1" : "=v"(r) : "v"(lp));
  return r;
}

// async global->LDS, 16B/lane; LDS dest = wave-uniform base + lane*16 (linear).
__device__ __forceinline__ void gll16(const void* g, void* l) {
  __builtin_amdgcn_global_load_lds((gvp)g, (svp)l, 16, 0, 0);
}

// ---------------- Kernel 0: f32 -> bf16 convert (x, Ww ONLY) ----------------
__global__ __launch_bounds__(256) void tobf16(const float* __restrict__ x,
                                              const float* __restrict__ ww,
                                              unsigned short* __restrict__ xB,
                                              unsigned short* __restrict__ wwB) {
  long i8 = (long)blockIdx.x * 256 + threadIdx.x;
  if (i8 < 1048576L) {
    f32x4 a = *(const f32x4*)(x + i8 * 8);
    f32x4 c = *(const f32x4*)(x + i8 * 8 + 4);
    u32x2 p0 = pack4(a), p1 = pack4(c);
    u32x4 o;
    o.x = p0.x; o.y = p0.y; o.z = p1.x; o.w = p1.y;
    *(u32x4*)(xB + i8 * 8) = o;
  } else {
    long k = i8 - 1048576L;   // 0..36863
    f32x4 a = *(const f32x4*)(ww + k * 8);
    f32x4 c = *(const f32x4*)(ww + k * 8 + 4);
    u32x2 p0 = pack4(a), p1 = pack4(c);
    u32x4 o;
    o.x = p0.x; o.y = p0.y; o.z = p1.x; o.w = p1.y;
    *(u32x4*)(wwB + k * 8) = o;
  }
}

// ---------------- Kernel 1: q = (xB @ WwB^T + b) * 0.125  +  wdkv permute ----------
// GEMM blocks 0..255: 2-COLUMN split (c0 = 0/144) -> xB read 2x not 3x (round-17).
// W tile 144x64 = 18 KB staged as 18x 1KB gll16: waves 0,1 issue 5, waves 2,3 issue
// 4 -> per-wave counted wait vmcnt(7)/vmcnt(6) (never drains own-step loads).
// Blocks 256..1407: wdkv f32 -> wdkvT tiled-image permute (consumed only by attn).
__global__ __launch_bounds__(256, 4) void qproj(const unsigned short* __restrict__ xB,
                                                const unsigned short* __restrict__ wwB,
                                                const float* __restrict__ Wb,
                                                unsigned short* __restrict__ q,
                                                const float* __restrict__ wdkv,
                                                unsigned short* __restrict__ wdkvT) {
  __shared__ unsigned short xl[2][64 * 64];    // 2 x 8 KB
  __shared__ unsigned short wl[2][144 * 64];   // 2 x 18 KB
  if (blockIdx.x >= 256) {
    long k = (long)(blockIdx.x - 256) * 256 + threadIdx.x;  // 0..294911
    int b = (int)(k / 73728);
    int rem = (int)(k % 73728);
    int srow = rem / 36;
    int l8 = rem - srow * 36;
    int st = srow >> 6;
    int s = srow & 63;
    int j = (l8 >> 1) * 2 + (s >> 5);
    int lane = ((s & 31) >> 2) * 8 + (s & 3) * 2 + (l8 & 1);
    f32x4 a = *(const f32x4*)(wdkv + k * 8);
    f32x4 c = *(const f32x4*)(wdkv + k * 8 + 4);
    u32x2 p0 = pack4(a), p1 = pack4(c);
    u32x4 o;
    o.x = p0.x; o.y = p0.y; o.z = p1.x; o.w = p1.y;
    *(u32x4*)((char*)wdkvT + (((long)(b * 32 + st) * 36 + j) << 10) + lane * 16) = o;
    return;
  }
  const int tid = threadIdx.x;
  const int lane = tid & 63;
  const int w = tid >> 6;
  const int g = lane >> 4;
  const int r = lane & 15;
  const int m0 = (blockIdx.x >> 1) * 64;
  const int c0 = (blockIdx.x & 1) * 144;

  const int o_i = (lane >> 3) * 2048 + (((lane & 7) * 16) ^ ((lane >> 3) << 4));

  // wave w handles W-instr j in [jw0, jw0+jwn): waves 0,1 -> 5; waves 2,3 -> 4.
  const int jwn = (w < 2) ? 5 : 4;
  const int jw0 = (w < 2) ? (w * 5) : (10 + (w - 2) * 4);

  f32x4 acc[9];
#pragma unroll
  for (int i = 0; i < 9; ++i) acc[i] = (f32x4)0.0f;

  const char* xsrc = (const char*)xB + (long)m0 * 2048;
  const char* wsrc = (const char*)wwB + (long)c0 * 2048;

#define QPROJ_ISSUE(kb2, cb)                                            \
  {                                                                     \
    char* xd = (char*)&xl[cb][0];                                       \
    char* wd = (char*)&wl[cb][0];                                       \
    _Pragma("unroll") for (int jj = 0; jj < 2; ++jj) {                  \
      int j = 2 * w + jj;                                               \
      gll16(xsrc + (long)j * 16384 + (kb2) + o_i, xd + j * 1024);       \
    }                                                                   \
    for (int jj = 0; jj < jwn; ++jj) {                                  \
      int j = jw0 + jj;                                                 \
      gll16(wsrc + (long)j * 16384 + (kb2) + o_i, wd + j * 1024);       \
    }                                                                   \
  }

  QPROJ_ISSUE(0, 0);
  for (int ks = 0; ks < 16; ++ks) {
    const int cb = ks & 1;
    if (ks < 15) {
      QPROJ_ISSUE((ks + 1) * 128, cb ^ 1);
      if (w < 2) {
        asm volatile("s_waitcnt vmcnt(7)" ::: "memory");
      } else {
        asm volatile("s_waitcnt vmcnt(6)" ::: "memory");
      }
    } else {
      asm volatile("s_waitcnt vmcnt(0)" ::: "memory");
    }
    __builtin_amdgcn_s_barrier();
    __builtin_amdgcn_sched_barrier(0);
    const char* xlb = (const char*)&xl[cb][0];
    const char* wlb = (const char*)&wl[cb][0];
#pragma unroll
    for (int kc = 0; kc < 2; ++kc) {
      int koff = kc * 64 + g * 16;
      bf16x8 a = as_bf(*(const u32x4*)(xlb + (16 * w + r) * 128 + (koff ^ ((r & 7) << 4))));
#pragma unroll
      for (int nf = 0; nf < 9; ++nf) {
        int l = nf * 16 + r;
        bf16x8 bb = as_bf(*(const u32x4*)(wlb + l * 128 + (koff ^ ((l & 7) << 4))));
        acc[nf] = mfma16(a, bb, acc[nf]);
      }
    }
    __builtin_amdgcn_sched_barrier(0);
    __builtin_amdgcn_s_barrier();
    __builtin_amdgcn_sched_barrier(0);
  }
  const int rowb = m0 + 16 * w + 4 * g;
#pragma unroll
  for (int nf = 0; nf < 9; ++nf) {
    int col = c0 + nf * 16 + r;
    float bias = Wb[col];
#pragma unroll
    for (int e = 0; e < 4; ++e) {
      float qv = (acc[nf][e] + bias) * 0.125f;
      q[(long)(rowb + e) * LL + col] = f2bf(qv);
    }
  }
}

// ---------------- Kernel 2: causal flash attn, swapped QK^T, 1 barrier/step --------
// Round-15 base + T13 defer-max: skip O-rescale and m-update when the tile max
// grows by <= 8 (wave-uniform __all); P bounded by e^8, bf16-safe. PV: 2-deep
// counted-lgkmcnt cluster pipeline. CH=5 -> 244 blocks <= 256 CUs.
__global__ __launch_bounds__(512, 2) void attn(const unsigned short* __restrict__ wdkvT,
                                               const unsigned short* __restrict__ q,
                                               float* __restrict__ out,
                                               char* __restrict__ partial,
                                               int CH, int SPB) {
  __shared__ unsigned short Vt[2][18 * 16 * 64];  // 2 x 36864 B, subtiled tr16 layout
  const int tid = threadIdx.x;
  const int lane = tid & 63;
  const int w = tid >> 6;
  const int g = lane >> 4;
  const int r = lane & 15;

  const int bid = blockIdx.x;
  const int b = bid / SPB;
  int rem = bid - b * SPB;
  int t = 0, base = 0, nch = 1;
  for (;;) {
    nch = (2 * t + 2 + CH - 1) / CH;
    if (rem < base + nch) break;
    base += nch;
    ++t;
  }
  const int c = rem - base;
  const bool direct = (nch == 1);
  const int q0 = t * 128;
  const int st0 = c * CH;
  const int st1 = min((c + 1) * CH, 2 * t + 2);

  char* vt0 = (char*)&Vt[0][0];
  char* vt1 = (char*)&Vt[1][0];

  const char* wsrcT = (const char*)wdkvT + (long)b * 32 * 36864;

  bf16x8 qf[9];
  {
    const long qrow = (long)b * TT + q0 + 16 * w + r;
#pragma unroll
    for (int kc = 0; kc < 9; ++kc)
      qf[kc] = as_bf(*(const u32x4*)(q + qrow * LL + kc * 32 + 8 * g));
  }

  f32x4 o[18];
#pragma unroll
  for (int i = 0; i < 18; ++i) o[i] = (f32x4)0.0f;
  float mr = -1e30f, lr = 0.0f;

#define ATTN_ISSUE(st_, dst_)                                          \
  {                                                                    \
    const char* srcT = wsrcT + (long)(st_) * 36864;                    \
    _Pragma("unroll") for (int jj = 0; jj < 5; ++jj) {                 \
      int j = w + 8 * jj;                                              \
      if (j < 36) gll16(srcT + j * 1024 + lane * 16, (dst_) + j * 1024);\
    }                                                                  \
  }

  const int rq = q0 + 16 * w + r;
  const int srcA = r + 32 * (g & 1);
  const int srcB = srcA + 16;
  const bool gsel = (g & 2) != 0;

  ATTN_ISSUE(st0, vt0);
  for (int st = st0; st < st1; ++st) {
    const int sb = st * 64;
    const int cbi = (st - st0) & 1;
    char* vtb = cbi ? vt1 : vt0;
    char* vtn = cbi ? vt0 : vt1;
    asm volatile("s_waitcnt vmcnt(0)" ::: "memory");
    __builtin_amdgcn_s_barrier();
    __builtin_amdgcn_sched_barrier(0);
    if (st + 1 < st1) ATTN_ISSUE(st + 1, vtn);
    // ---- swapped QK^T: sa[sf][e] = S[s = sb+16sf+4g+e][q = rq] ----
    f32x4 sa[4];
#pragma unroll
    for (int i = 0; i < 4; ++i) sa[i] = (f32x4)0.0f;
    __builtin_amdgcn_s_setprio(1);
#pragma unroll
    for (int kc = 0; kc < 9; ++kc) {
      const int lblk2048 = (2 * kc + (g >> 1)) * 2048;
      const int lrem16 = (g & 1) * 16;
#pragma unroll
      for (int sf = 0; sf < 4; ++sf) {
        bf16x8 vv = as_bf(*(const u32x4*)(vtb + lblk2048 + (4 * sf + (r >> 2)) * 128 + (r & 3) * 32 + lrem16));
        sa[sf] = mfma16(vv, qf[kc], sa[sf]);
      }
    }
    __builtin_amdgcn_s_setprio(0);
    // ---- mask + per-lane rowmax ----
    float tm = -1e30f;
#pragma unroll
    for (int sf = 0; sf < 4; ++sf)
#pragma unroll
      for (int e = 0; e < 4; ++e) {
        int sg = sb + 16 * sf + 4 * g + e;
        if (sg > rq) sa[sf][e] = -1e30f;
        tm = fmaxf(tm, sa[sf][e]);
      }
    tm = fmaxf(tm, __shfl_xor(tm, 16));
    tm = fmaxf(tm, __shfl_xor(tm, 32));
    // ---- T13 defer-max: only rescale when max grows by > 8 ----
    const bool upd = !__all(tm <= mr + 8.0f);
    float al = 1.0f;
    if (upd) {
      const float mn = fmaxf(mr, tm);
      al = __expf(mr - mn);
      mr = mn;
    }
    float rs = 0.0f;
#pragma unroll
    for (int sf = 0; sf < 4; ++sf)
#pragma unroll
      for (int e = 0; e < 4; ++e) {
        float pv = __expf(sa[sf][e] - mr);
        sa[sf][e] = pv;
        rs += pv;
      }
    rs += __shfl_xor(rs, 16);
    rs += __shfl_xor(rs, 32);
    lr = lr * al + rs;
    if (upd) {
      float alr[4];
#pragma unroll
      for (int e = 0; e < 4; ++e) alr[e] = __shfl(al, 4 * g + e);
#pragma unroll
      for (int nf = 0; nf < 18; ++nf)
#pragma unroll
        for (int e = 0; e < 4; ++e) o[nf][e] *= alr[e];
    }
    // ---- pack P to bf16 pairs ----
    unsigned pk[4][2];
#pragma unroll
    for (int sf = 0; sf < 4; ++sf) {
      pk[sf][0] = cvtpk(sa[sf][0], sa[sf][1]);
      pk[sf][1] = cvtpk(sa[sf][2], sa[sf][3]);
    }
    // ---- precompute BOTH PV A-fragments ----
    bf16x8 paK0, paK1;
#pragma unroll
    for (int kc2 = 0; kc2 < 2; ++kc2) {
      int xa0 = __shfl((int)pk[2 * kc2 + 0][0], srcA);
      int xb0 = __shfl((int)pk[2 * kc2 + 1][0], srcA);
      int xa1 = __shfl((int)pk[2 * kc2 + 0][1], srcA);
      int xb1 = __shfl((int)pk[2 * kc2 + 1][1], srcA);
      int ya0 = __shfl((int)pk[2 * kc2 + 0][0], srcB);
      int yb0 = __shfl((int)pk[2 * kc2 + 1][0], srcB);
      int ya1 = __shfl((int)pk[2 * kc2 + 0][1], srcB);
      int yb1 = __shfl((int)pk[2 * kc2 + 1][1], srcB);
      u32x4 pd;
      pd.x = (unsigned)(gsel ? xb0 : xa0);
      pd.y = (unsigned)(gsel ? xb1 : xa1);
      pd.z = (unsigned)(gsel ? yb0 : ya0);
      pd.w = (unsigned)(gsel ? yb1 : ya1);
      if (kc2 == 0) paK0 = as_bf(pd); else paK1 = as_bf(pd);
    }
    asm volatile("" : "+v"(paK0), "+v"(paK1));
    // drain shuffle bpermutes so the counted FIFO below holds only tr16s
    asm volatile("s_waitcnt lgkmcnt(0)" ::: "memory");
    __builtin_amdgcn_sched_barrier(0);
    // ---- PV: 12 clusters (kc2 x gg), 2-deep counted-lgkmcnt pipeline ----
    s16x4 tq[2][6];
#define PV_CL(c_, sl_)                                                      \
    {                                                                       \
      const int kc2_ = (c_) / 6, gg_ = (c_) % 6;                            \
      const char* ap = vtb + kc2_ * 1024 + g * 256 + r * 8;                 \
      _Pragma("unroll") for (int i = 0; i < 3; ++i) {                       \
        int nf_ = gg_ * 3 + i;                                              \
        tq[sl_][2 * i] = tr16(ap + nf_ * 2048);                             \
        tq[sl_][2 * i + 1] = tr16(ap + nf_ * 2048 + 128);                   \
      }                                                                     \
    }
    __builtin_amdgcn_s_setprio(1);
    PV_CL(0, 0);
#pragma unroll
    for (int c2 = 0; c2 < 12; ++c2) {
      if (c2 < 11) {
        PV_CL(c2 + 1, (c2 + 1) & 1);
        asm volatile("s_waitcnt lgkmcnt(6)" ::: "memory");
      } else {
        asm volatile("s_waitcnt lgkmcnt(0)" ::: "memory");
      }
      __builtin_amdgcn_sched_barrier(0);
      const int gg_ = c2 % 6;
      const bf16x8 pa = (c2 < 6) ? paK0 : paK1;
#pragma unroll
      for (int i = 0; i < 3; ++i) {
        int nf = gg_ * 3 + i;
        s16x4 t0 = tq[c2 & 1][2 * i], t1 = tq[c2 & 1][2 * i + 1];
        bf16x8 bb;
        bb[0] = t0[0]; bb[1] = t0[1]; bb[2] = t0[2]; bb[3] = t0[3];
        bb[4] = t1[0]; bb[5] = t1[1]; bb[6] = t1[2]; bb[7] = t1[3];
        o[nf] = mfma16(pa, bb, o[nf]);
      }
    }
    __builtin_amdgcn_s_setprio(0);
  }
  // ---- epilogue ----
  if (direct) {
    float lrr[4];
#pragma unroll
    for (int e = 0; e < 4; ++e) lrr[e] = __shfl(lr, 4 * g + e);
    const long trow = (long)b * TT + q0 + 16 * w + 4 * g;
#pragma unroll
    for (int nf = 0; nf < 18; ++nf) {
      int col = 16 * nf + r;
#pragma unroll
      for (int e = 0; e < 4; ++e)
        out[(trow + e) * LL + col] = o[nf][e] / lrr[e];
    }
  } else {
    char* sp = partial + (size_t)(b * SPB + rem) * SLOTB2;
    if (g == 0) {
      ((float*)sp)[16 * w + r] = mr;
      ((float*)(sp + 512))[16 * w + r] = lr;
    }
#pragma unroll
    for (int p = 0; p < 9; ++p) {
      u32x2 a0 = pack4(o[2 * p]);
      u32x2 a1 = pack4(o[2 * p + 1]);
      u32x4 v;
      v.x = a0.x; v.y = a0.y; v.z = a1.x; v.w = a1.y;
      *(u32x4*)(sp + 1024 + p * 8192 + tid * 16) = v;
    }
  }
}

// ---------------- Kernel 3: combine partials in FRAGMENT space ----------------
__global__ __launch_bounds__(512) void reduce_k(const char* __restrict__ partial,
                                                float* __restrict__ out,
                                                int CH, int SPB, int NMT) {
  const int bid = blockIdx.x;
  const int nfl = bid % 9;
  const int rest = bid / 9;
  const int b = rest / NMT;
  int idx = rest % NMT;
  int t = 0, base = 0, nch = 1;
  for (;;) {
    nch = (2 * t + 2 + CH - 1) / CH;
    if (nch > 1) {
      if (idx == 0) break;
      --idx;
    }
    base += nch;
    ++t;
  }
  const char* sp0 = partial + (size_t)(b * SPB + base) * SLOTB2;

  const int tid = threadIdx.x;
  const int w = tid >> 6;
  const int g = (tid & 63) >> 4;
  const int r = tid & 15;
  const int row0 = 16 * w + 4 * g;

  float M[4], Lx[4], acc[8];
#pragma unroll
  for (int e = 0; e < 4; ++e) { M[e] = -1e30f; Lx[e] = 0.0f; }
#pragma unroll
  for (int k = 0; k < 8; ++k) acc[k] = 0.0f;

  for (int i = 0; i < nch; ++i) {
    const char* sp = sp0 + (size_t)i * SLOTB2;
    const float* mv = (const float*)sp;
    const float* lv = (const float*)(sp + 512);
    u32x4 v = *(const u32x4*)(sp + 1024 + nfl * 8192 + tid * 16);
    const unsigned short* pu = (const unsigned short*)&v;
    float fo[4], fi[4];
#pragma unroll
    for (int e = 0; e < 4; ++e) {
      float mi = mv[row0 + e];
      float mn = fmaxf(M[e], mi);
      fo[e] = __expf(M[e] - mn);
      fi[e] = __expf(mi - mn);
      Lx[e] = Lx[e] * fo[e] + fi[e] * lv[row0 + e];
      M[e] = mn;
    }
#pragma unroll
    for (int k = 0; k < 8; ++k)
      acc[k] = acc[k] * fo[k & 3] + fi[k & 3] * __uint_as_float((unsigned)pu[k] << 16);
  }
#pragma unroll
  for (int k = 0; k < 8; ++k) {
    int row = row0 + (k & 3);
    int col = 16 * (2 * nfl + (k >> 2)) + r;
    out[((size_t)b * TT + t * 128 + row) * LL + col] = acc[k] / Lx[k & 3];
  }
}

extern "C" void kernel_launch(void* const* d_in, const int* in_sizes, int n_in,
                              void* d_out, int out_size, void* d_ws, size_t ws_size,
                              hipStream_t stream) {
  const float* x = (const float*)d_in[0];
  const float* Wdkv = (const float*)d_in[1];
  const float* Ww = (const float*)d_in[2];
  const float* Wb = (const float*)d_in[3];
  float* outp = (float*)d_out;

  char* ws = (char*)d_ws;
  unsigned short* qB = (unsigned short*)ws;                  // 4,718,592 B
  unsigned short* xB = (unsigned short*)(ws + 4718592);      // 16,777,216 B
  unsigned short* wdkvT = (unsigned short*)(ws + 21495808);  // 4,718,592 B (tiled image)
  unsigned short* wwB = (unsigned short*)(ws + 26214400);    // 589,824 B
  char* partialB = ws + 26804224;

  // CH ladder: CH=5 -> SPB=61 -> 244 blocks <= 256 CUs (1 block/CU; round-11 lesson).
  int CH = 32, SPB = 16;
  const int chs[4] = {5, 8, 16, 32};
  for (int ci = 0; ci < 4; ++ci) {
    int ch = chs[ci];
    int spb = 0;
    for (int t = 0; t < 16; ++t) spb += (2 * t + 2 + ch - 1) / ch;
    if (26804224 + (size_t)4 * spb * SLOTB2 <= ws_size) { CH = ch; SPB = spb; break; }
  }
  int NMT = 0;
  for (int t = 0; t < 16; ++t)
    if ((2 * t + 2 + CH - 1) / CH > 1) ++NMT;

  tobf16<<<4240, 256, 0, stream>>>(x, Ww, xB, wwB);
  qproj<<<1408, 256, 0, stream>>>(xB, wwB, Wb, qB, Wdkv, wdkvT);
  attn<<<4 * SPB, 512, 0, stream>>>(wdkvT, qB, outp, partialB, CH, SPB);
  if (NMT > 0) reduce_k<<<4 * NMT * 9, 512, 0, stream>>>(partialB, outp, CH, SPB, NMT);
}

// Round 18
// 62.919 us; speedup vs baseline: 1.0767x; 1.0767x over previous
//
#include <hip/hip_runtime.h>

#define TT 2048
#define LL 288
#define CC 1024
#define SLOTB2 74752  // 128-row partial: m[128]f32 + l[128]f32 + O-blob [9][512][16B] bf16

typedef __attribute__((ext_vector_type(8))) short bf16x8;
typedef __attribute__((ext_vector_type(4))) float f32x4;
typedef __attribute__((ext_vector_type(4))) unsigned int u32x4;
typedef __attribute__((ext_vector_type(2))) unsigned int u32x2;
typedef __attribute__((ext_vector_type(4))) short s16x4;

__device__ __forceinline__ unsigned short f2bf(float f) {
  unsigned u = __float_as_uint(f);
  u += 0x7fffu + ((u >> 16) & 1u);
  return (unsigned short)(u >> 16);
}

__device__ __forceinline__ u32x2 pack4(f32x4 v) {
  u32x2 p;
  p.x = (unsigned)f2bf(v.x) | ((unsigned)f2bf(v.y) << 16);
  p.y = (unsigned)f2bf(v.z) | ((unsigned)f2bf(v.w) << 16);
  return p;
}

__device__ __forceinline__ f32x4 mfma16(bf16x8 a, bf16x8 b, f32x4 c) {
  return __builtin_amdgcn_mfma_f32_16x16x32_bf16(a, b, c, 0, 0, 0);
}

__device__ __forceinline__ bf16x8 as_bf(u32x4 u) {
  return __builtin_bit_cast(bf16x8, u);
}

// packed bf16 convert: dword = {bf16(lo) | bf16(hi)<<16}
__device__ __forceinline__ unsigned cvtpk(float lo, float hi) {
  unsigned d;
  asm("v_cvt_pk_bf16_f32 %0, %1, %2" : "=v"(d) : "v"(lo), "v"(hi));
  return d;
}

typedef __attribute__((address_space(3))) const unsigned short* lds_cptr;
typedef __attribute__((address_space(1))) const void* gvp;
typedef __attribute__((address_space(3))) void* svp;

// ds_read_b64_tr_b16: lane fetches 8B at its own addr (subtile base + (lane&15)*8);
// HW transposes within 16-lane groups: lane c elem j holds tile[j][c] of [4][16] bf16.
__device__ __forceinline__ s16x4 tr16(const void* p) {
  s16x4 r;
  lds_cptr lp = (lds_cptr)p;
  asm volatile("ds_read_b64_tr_b16 %0, %1" : "=v"(r) : "v"(lp));
  return r;
}

// async global->LDS, 16B/lane; LDS dest = wave-uniform base + lane*16 (linear).
__device__ __forceinline__ void gll16(const void* g, void* l) {
  __builtin_amdgcn_global_load_lds((gvp)g, (svp)l, 16, 0, 0);
}

// ---------------- Kernel 0: f32 -> bf16 convert (x, Ww ONLY) ----------------
// wdkv permute moved into the qproj dispatch as extra blocks (round-16: it is only
// consumed by attn, so it need not serialize before qproj).
__global__ __launch_bounds__(256) void tobf16(const float* __restrict__ x,
                                              const float* __restrict__ ww,
                                              unsigned short* __restrict__ xB,
                                              unsigned short* __restrict__ wwB) {
  long i8 = (long)blockIdx.x * 256 + threadIdx.x;
  if (i8 < 1048576L) {
    f32x4 a = *(const f32x4*)(x + i8 * 8);
    f32x4 c = *(const f32x4*)(x + i8 * 8 + 4);
    u32x2 p0 = pack4(a), p1 = pack4(c);
    u32x4 o;
    o.x = p0.x; o.y = p0.y; o.z = p1.x; o.w = p1.y;
    *(u32x4*)(xB + i8 * 8) = o;
  } else {
    long k = i8 - 1048576L;   // 0..36863
    f32x4 a = *(const f32x4*)(ww + k * 8);
    f32x4 c = *(const f32x4*)(ww + k * 8 + 4);
    u32x2 p0 = pack4(a), p1 = pack4(c);
    u32x4 o;
    o.x = p0.x; o.y = p0.y; o.z = p1.x; o.w = p1.y;
    *(u32x4*)(wwB + k * 8) = o;
  }
}

// ---------------- Kernel 1: q = (xB @ WwB^T + b) * 0.125  +  wdkv permute ----------
// Blocks 0..383: round-12 proven GEMM (gll16 both operands, vmcnt(5) slack).
// Blocks 384..1535: wdkv f32 -> wdkvT tiled-image permute (independent work that
// overlaps the GEMM's pipeline; consumed only by attn, the NEXT kernel).
// wdkvT image: byte j*1024+lane*16 holds Wdkv[b][st*64+s][l0..l0+7] with
// s=(j&1)*32+4*(lane>>3)+((lane>>1)&3), l0=(j>>1)*16+(lane&1)*8.
__global__ __launch_bounds__(256, 4) void qproj(const unsigned short* __restrict__ xB,
                                                const unsigned short* __restrict__ wwB,
                                                const float* __restrict__ Wb,
                                                unsigned short* __restrict__ q,
                                                const float* __restrict__ wdkv,
                                                unsigned short* __restrict__ wdkvT) {
  __shared__ unsigned short xl[2][64 * 64];
  __shared__ unsigned short wl[2][96 * 64];
  if (blockIdx.x >= 384) {
    // ---- wdkv permute block ----
    long k = (long)(blockIdx.x - 384) * 256 + threadIdx.x;  // 0..294911
    int b = (int)(k / 73728);
    int rem = (int)(k % 73728);
    int srow = rem / 36;
    int l8 = rem - srow * 36;
    int st = srow >> 6;
    int s = srow & 63;
    int j = (l8 >> 1) * 2 + (s >> 5);
    int lane = ((s & 31) >> 2) * 8 + (s & 3) * 2 + (l8 & 1);
    f32x4 a = *(const f32x4*)(wdkv + k * 8);
    f32x4 c = *(const f32x4*)(wdkv + k * 8 + 4);
    u32x2 p0 = pack4(a), p1 = pack4(c);
    u32x4 o;
    o.x = p0.x; o.y = p0.y; o.z = p1.x; o.w = p1.y;
    *(u32x4*)((char*)wdkvT + (((long)(b * 32 + st) * 36 + j) << 10) + lane * 16) = o;
    return;
  }
  const int tid = threadIdx.x;
  const int lane = tid & 63;
  const int w = tid >> 6;
  const int g = lane >> 4;
  const int r = lane & 15;
  const int m0 = (blockIdx.x / 3) * 64;
  const int c0 = (blockIdx.x % 3) * 96;

  const int o_i = (lane >> 3) * 2048 + (((lane & 7) * 16) ^ ((lane >> 3) << 4));

  f32x4 acc[6];
#pragma unroll
  for (int i = 0; i < 6; ++i) acc[i] = (f32x4)0.0f;

  const char* xsrc = (const char*)xB + (long)m0 * 2048;
  const char* wsrc = (const char*)wwB + (long)c0 * 2048;

#define QPROJ_ISSUE(kb2, cb)                                            \
  {                                                                     \
    char* xd = (char*)&xl[cb][0];                                       \
    char* wd = (char*)&wl[cb][0];                                       \
    _Pragma("unroll") for (int jj = 0; jj < 2; ++jj) {                  \
      int j = 2 * w + jj;                                               \
      gll16(xsrc + (long)j * 16384 + (kb2) + o_i, xd + j * 1024);       \
    }                                                                   \
    _Pragma("unroll") for (int jj = 0; jj < 3; ++jj) {                  \
      int j = 3 * w + jj;                                               \
      gll16(wsrc + (long)j * 16384 + (kb2) + o_i, wd + j * 1024);       \
    }                                                                   \
  }

  QPROJ_ISSUE(0, 0);
  for (int ks = 0; ks < 16; ++ks) {
    const int cb = ks & 1;
    if (ks < 15) {
      QPROJ_ISSUE((ks + 1) * 128, cb ^ 1);
      asm volatile("s_waitcnt vmcnt(5)" ::: "memory");
    } else {
      asm volatile("s_waitcnt vmcnt(0)" ::: "memory");
    }
    __builtin_amdgcn_s_barrier();
    __builtin_amdgcn_sched_barrier(0);
    const char* xlb = (const char*)&xl[cb][0];
    const char* wlb = (const char*)&wl[cb][0];
#pragma unroll
    for (int kc = 0; kc < 2; ++kc) {
      int koff = kc * 64 + g * 16;
      bf16x8 a = as_bf(*(const u32x4*)(xlb + (16 * w + r) * 128 + (koff ^ ((r & 7) << 4))));
#pragma unroll
      for (int nf = 0; nf < 6; ++nf) {
        int l = nf * 16 + r;
        bf16x8 bb = as_bf(*(const u32x4*)(wlb + l * 128 + (koff ^ ((l & 7) << 4))));
        acc[nf] = mfma16(a, bb, acc[nf]);
      }
    }
    __builtin_amdgcn_sched_barrier(0);
    __builtin_amdgcn_s_barrier();
    __builtin_amdgcn_sched_barrier(0);
  }
  const int rowb = m0 + 16 * w + 4 * g;
#pragma unroll
  for (int nf = 0; nf < 6; ++nf) {
    int col = c0 + nf * 16 + r;
    float bias = Wb[col];
#pragma unroll
    for (int e = 0; e < 4; ++e) {
      float qv = (acc[nf][e] + bias) * 0.125f;
      q[(long)(rowb + e) * LL + col] = f2bf(qv);
    }
  }
}

// ---------------- Kernel 2: causal flash attn, swapped QK^T, 1 barrier/step --------
// Round-15 form (best measured): swapped QK^T, in-register P exchange, PV 2-deep
// counted-lgkmcnt cluster pipeline. CH=5 -> 244 blocks <= 256 CUs.
__global__ __launch_bounds__(512, 2) void attn(const unsigned short* __restrict__ wdkvT,
                                               const unsigned short* __restrict__ q,
                                               float* __restrict__ out,
                                               char* __restrict__ partial,
                                               int CH, int SPB) {
  __shared__ unsigned short Vt[2][18 * 16 * 64];  // 2 x 36864 B, subtiled tr16 layout
  const int tid = threadIdx.x;
  const int lane = tid & 63;
  const int w = tid >> 6;
  const int g = lane >> 4;
  const int r = lane & 15;

  const int bid = blockIdx.x;
  const int b = bid / SPB;
  int rem = bid - b * SPB;
  int t = 0, base = 0, nch = 1;
  for (;;) {
    nch = (2 * t + 2 + CH - 1) / CH;
    if (rem < base + nch) break;
    base += nch;
    ++t;
  }
  const int c = rem - base;
  const bool direct = (nch == 1);
  const int q0 = t * 128;
  const int st0 = c * CH;
  const int st1 = min((c + 1) * CH, 2 * t + 2);

  char* vt0 = (char*)&Vt[0][0];
  char* vt1 = (char*)&Vt[1][0];

  const char* wsrcT = (const char*)wdkvT + (long)b * 32 * 36864;

  bf16x8 qf[9];
  {
    const long qrow = (long)b * TT + q0 + 16 * w + r;
#pragma unroll
    for (int kc = 0; kc < 9; ++kc)
      qf[kc] = as_bf(*(const u32x4*)(q + qrow * LL + kc * 32 + 8 * g));
  }

  f32x4 o[18];
#pragma unroll
  for (int i = 0; i < 18; ++i) o[i] = (f32x4)0.0f;
  float mr = -1e30f, lr = 0.0f;

#define ATTN_ISSUE(st_, dst_)                                          \
  {                                                                    \
    const char* srcT = wsrcT + (long)(st_) * 36864;                    \
    _Pragma("unroll") for (int jj = 0; jj < 5; ++jj) {                 \
      int j = w + 8 * jj;                                              \
      if (j < 36) gll16(srcT + j * 1024 + lane * 16, (dst_) + j * 1024);\
    }                                                                  \
  }

  const int rq = q0 + 16 * w + r;
  const int srcA = r + 32 * (g & 1);
  const int srcB = srcA + 16;
  const bool gsel = (g & 2) != 0;

  ATTN_ISSUE(st0, vt0);
  for (int st = st0; st < st1; ++st) {
    const int sb = st * 64;
    const int cbi = (st - st0) & 1;
    char* vtb = cbi ? vt1 : vt0;
    char* vtn = cbi ? vt0 : vt1;
    asm volatile("s_waitcnt vmcnt(0)" ::: "memory");
    __builtin_amdgcn_s_barrier();
    __builtin_amdgcn_sched_barrier(0);
    if (st + 1 < st1) ATTN_ISSUE(st + 1, vtn);
    // ---- swapped QK^T: sa[sf][e] = S[s = sb+16sf+4g+e][q = rq] ----
    f32x4 sa[4];
#pragma unroll
    for (int i = 0; i < 4; ++i) sa[i] = (f32x4)0.0f;
    __builtin_amdgcn_s_setprio(1);
#pragma unroll
    for (int kc = 0; kc < 9; ++kc) {
      const int lblk2048 = (2 * kc + (g >> 1)) * 2048;
      const int lrem16 = (g & 1) * 16;
#pragma unroll
      for (int sf = 0; sf < 4; ++sf) {
        bf16x8 vv = as_bf(*(const u32x4*)(vtb + lblk2048 + (4 * sf + (r >> 2)) * 128 + (r & 3) * 32 + lrem16));
        sa[sf] = mfma16(vv, qf[kc], sa[sf]);
      }
    }
    __builtin_amdgcn_s_setprio(0);
    // ---- mask + per-lane rowmax ----
    float tm = -1e30f;
#pragma unroll
    for (int sf = 0; sf < 4; ++sf)
#pragma unroll
      for (int e = 0; e < 4; ++e) {
        int sg = sb + 16 * sf + 4 * g + e;
        if (sg > rq) sa[sf][e] = -1e30f;
        tm = fmaxf(tm, sa[sf][e]);
      }
    tm = fmaxf(tm, __shfl_xor(tm, 16));
    tm = fmaxf(tm, __shfl_xor(tm, 32));
    const float mn = fmaxf(mr, tm);
    const float al = __expf(mr - mn);
    mr = mn;
    float rs = 0.0f;
#pragma unroll
    for (int sf = 0; sf < 4; ++sf)
#pragma unroll
      for (int e = 0; e < 4; ++e) {
        float pv = __expf(sa[sf][e] - mn);
        sa[sf][e] = pv;
        rs += pv;
      }
    rs += __shfl_xor(rs, 16);
    rs += __shfl_xor(rs, 32);
    lr = lr * al + rs;
    float alr[4];
#pragma unroll
    for (int e = 0; e < 4; ++e) alr[e] = __shfl(al, 4 * g + e);
#pragma unroll
    for (int nf = 0; nf < 18; ++nf)
#pragma unroll
      for (int e = 0; e < 4; ++e) o[nf][e] *= alr[e];
    // ---- pack P to bf16 pairs ----
    unsigned pk[4][2];
#pragma unroll
    for (int sf = 0; sf < 4; ++sf) {
      pk[sf][0] = cvtpk(sa[sf][0], sa[sf][1]);
      pk[sf][1] = cvtpk(sa[sf][2], sa[sf][3]);
    }
    // ---- precompute BOTH PV A-fragments ----
    bf16x8 paK0, paK1;
#pragma unroll
    for (int kc2 = 0; kc2 < 2; ++kc2) {
      int xa0 = __shfl((int)pk[2 * kc2 + 0][0], srcA);
      int xb0 = __shfl((int)pk[2 * kc2 + 1][0], srcA);
      int xa1 = __shfl((int)pk[2 * kc2 + 0][1], srcA);
      int xb1 = __shfl((int)pk[2 * kc2 + 1][1], srcA);
      int ya0 = __shfl((int)pk[2 * kc2 + 0][0], srcB);
      int yb0 = __shfl((int)pk[2 * kc2 + 1][0], srcB);
      int ya1 = __shfl((int)pk[2 * kc2 + 0][1], srcB);
      int yb1 = __shfl((int)pk[2 * kc2 + 1][1], srcB);
      u32x4 pd;
      pd.x = (unsigned)(gsel ? xb0 : xa0);
      pd.y = (unsigned)(gsel ? xb1 : xa1);
      pd.z = (unsigned)(gsel ? yb0 : ya0);
      pd.w = (unsigned)(gsel ? yb1 : ya1);
      if (kc2 == 0) paK0 = as_bf(pd); else paK1 = as_bf(pd);
    }
    asm volatile("" : "+v"(paK0), "+v"(paK1));
    // drain shuffle bpermutes so the counted FIFO below holds only tr16s
    asm volatile("s_waitcnt lgkmcnt(0)" ::: "memory");
    __builtin_amdgcn_sched_barrier(0);
    // ---- PV: 12 clusters (kc2 x gg), 2-deep counted-lgkmcnt pipeline ----
    s16x4 tq[2][6];
#define PV_CL(c_, sl_)                                                      \
    {                                                                       \
      const int kc2_ = (c_) / 6, gg_ = (c_) % 6;                            \
      const char* ap = vtb + kc2_ * 1024 + g * 256 + r * 8;                 \
      _Pragma("unroll") for (int i = 0; i < 3; ++i) {                       \
        int nf_ = gg_ * 3 + i;                                              \
        tq[sl_][2 * i] = tr16(ap + nf_ * 2048);                             \
        tq[sl_][2 * i + 1] = tr16(ap + nf_ * 2048 + 128);                   \
      }                                                                     \
    }
    __builtin_amdgcn_s_setprio(1);
    PV_CL(0, 0);
#pragma unroll
    for (int c2 = 0; c2 < 12; ++c2) {
      if (c2 < 11) {
        PV_CL(c2 + 1, (c2 + 1) & 1);
        asm volatile("s_waitcnt lgkmcnt(6)" ::: "memory");
      } else {
        asm volatile("s_waitcnt lgkmcnt(0)" ::: "memory");
      }
      __builtin_amdgcn_sched_barrier(0);
      const int gg_ = c2 % 6;
      const bf16x8 pa = (c2 < 6) ? paK0 : paK1;
#pragma unroll
      for (int i = 0; i < 3; ++i) {
        int nf = gg_ * 3 + i;
        s16x4 t0 = tq[c2 & 1][2 * i], t1 = tq[c2 & 1][2 * i + 1];
        bf16x8 bb;
        bb[0] = t0[0]; bb[1] = t0[1]; bb[2] = t0[2]; bb[3] = t0[3];
        bb[4] = t1[0]; bb[5] = t1[1]; bb[6] = t1[2]; bb[7] = t1[3];
        o[nf] = mfma16(pa, bb, o[nf]);
      }
    }
    __builtin_amdgcn_s_setprio(0);
  }
  // ---- epilogue ----
  if (direct) {
    float lrr[4];
#pragma unroll
    for (int e = 0; e < 4; ++e) lrr[e] = __shfl(lr, 4 * g + e);
    const long trow = (long)b * TT + q0 + 16 * w + 4 * g;
#pragma unroll
    for (int nf = 0; nf < 18; ++nf) {
      int col = 16 * nf + r;
#pragma unroll
      for (int e = 0; e < 4; ++e)
        out[(trow + e) * LL + col] = o[nf][e] / lrr[e];
    }
  } else {
    char* sp = partial + (size_t)(b * SPB + rem) * SLOTB2;
    if (g == 0) {
      ((float*)sp)[16 * w + r] = mr;
      ((float*)(sp + 512))[16 * w + r] = lr;
    }
#pragma unroll
    for (int p = 0; p < 9; ++p) {
      u32x2 a0 = pack4(o[2 * p]);
      u32x2 a1 = pack4(o[2 * p + 1]);
      u32x4 v;
      v.x = a0.x; v.y = a0.y; v.z = a1.x; v.w = a1.y;
      *(u32x4*)(sp + 1024 + p * 8192 + tid * 16) = v;
    }
  }
}

// ---------------- Kernel 3: combine partials in FRAGMENT space ----------------
__global__ __launch_bounds__(512) void reduce_k(const char* __restrict__ partial,
                                                float* __restrict__ out,
                                                int CH, int SPB, int NMT) {
  const int bid = blockIdx.x;
  const int nfl = bid % 9;
  const int rest = bid / 9;
  const int b = rest / NMT;
  int idx = rest % NMT;
  int t = 0, base = 0, nch = 1;
  for (;;) {
    nch = (2 * t + 2 + CH - 1) / CH;
    if (nch > 1) {
      if (idx == 0) break;
      --idx;
    }
    base += nch;
    ++t;
  }
  const char* sp0 = partial + (size_t)(b * SPB + base) * SLOTB2;

  const int tid = threadIdx.x;
  const int w = tid >> 6;
  const int g = (tid & 63) >> 4;
  const int r = tid & 15;
  const int row0 = 16 * w + 4 * g;

  float M[4], Lx[4], acc[8];
#pragma unroll
  for (int e = 0; e < 4; ++e) { M[e] = -1e30f; Lx[e] = 0.0f; }
#pragma unroll
  for (int k = 0; k < 8; ++k) acc[k] = 0.0f;

  for (int i = 0; i < nch; ++i) {
    const char* sp = sp0 + (size_t)i * SLOTB2;
    const float* mv = (const float*)sp;
    const float* lv = (const float*)(sp + 512);
    u32x4 v = *(const u32x4*)(sp + 1024 + nfl * 8192 + tid * 16);
    const unsigned short* pu = (const unsigned short*)&v;
    float fo[4], fi[4];
#pragma unroll
    for (int e = 0; e < 4; ++e) {
      float mi = mv[row0 + e];
      float mn = fmaxf(M[e], mi);
      fo[e] = __expf(M[e] - mn);
      fi[e] = __expf(mi - mn);
      Lx[e] = Lx[e] * fo[e] + fi[e] * lv[row0 + e];
      M[e] = mn;
    }
#pragma unroll
    for (int k = 0; k < 8; ++k)
      acc[k] = acc[k] * fo[k & 3] + fi[k & 3] * __uint_as_float((unsigned)pu[k] << 16);
  }
#pragma unroll
  for (int k = 0; k < 8; ++k) {
    int row = row0 + (k & 3);
    int col = 16 * (2 * nfl + (k >> 2)) + r;
    out[((size_t)b * TT + t * 128 + row) * LL + col] = acc[k] / Lx[k & 3];
  }
}

extern "C" void kernel_launch(void* const* d_in, const int* in_sizes, int n_in,
                              void* d_out, int out_size, void* d_ws, size_t ws_size,
                              hipStream_t stream) {
  const float* x = (const float*)d_in[0];
  const float* Wdkv = (const float*)d_in[1];
  const float* Ww = (const float*)d_in[2];
  const float* Wb = (const float*)d_in[3];
  float* outp = (float*)d_out;

  char* ws = (char*)d_ws;
  unsigned short* qB = (unsigned short*)ws;                  // 4,718,592 B
  unsigned short* xB = (unsigned short*)(ws + 4718592);      // 16,777,216 B
  unsigned short* wdkvT = (unsigned short*)(ws + 21495808);  // 4,718,592 B (tiled image)
  unsigned short* wwB = (unsigned short*)(ws + 26214400);    // 589,824 B
  char* partialB = ws + 26804224;

  // CH ladder: CH=5 -> SPB=61 -> 244 blocks <= 256 CUs (1 block/CU; round-11 lesson).
  int CH = 32, SPB = 16;
  const int chs[4] = {5, 8, 16, 32};
  for (int ci = 0; ci < 4; ++ci) {
    int ch = chs[ci];
    int spb = 0;
    for (int t = 0; t < 16; ++t) spb += (2 * t + 2 + ch - 1) / ch;
    if (26804224 + (size_t)4 * spb * SLOTB2 <= ws_size) { CH = ch; SPB = spb; break; }
  }
  int NMT = 0;
  for (int t = 0; t < 16; ++t)
    if ((2 * t + 2 + CH - 1) / CH > 1) ++NMT;

  tobf16<<<4240, 256, 0, stream>>>(x, Ww, xB, wwB);
  qproj<<<1536, 256, 0, stream>>>(xB, wwB, Wb, qB, Wdkv, wdkvT);
  attn<<<4 * SPB, 512, 0, stream>>>(wdkvT, qB, outp, partialB, CH, SPB);
  if (NMT > 0) reduce_k<<<4 * NMT * 9, 512, 0, stream>>>(partialB, outp, CH, SPB, NMT);
}

// Round 19
// 61.712 us; speedup vs baseline: 1.0978x; 1.0196x over previous
//
#include <hip/hip_runtime.h>

#define TT 2048
#define LL 288
#define CC 1024
#define SLOTB2 74752  // 128-row partial: m[128]f32 + l[128]f32 + O-blob [9][512][16B] bf16

typedef __attribute__((ext_vector_type(8))) short bf16x8;
typedef __attribute__((ext_vector_type(4))) float f32x4;
typedef __attribute__((ext_vector_type(4))) unsigned int u32x4;
typedef __attribute__((ext_vector_type(2))) unsigned int u32x2;
typedef __attribute__((ext_vector_type(4))) short s16x4;

__device__ __forceinline__ unsigned short f2bf(float f) {
  unsigned u = __float_as_uint(f);
  u += 0x7fffu + ((u >> 16) & 1u);
  return (unsigned short)(u >> 16);
}

__device__ __forceinline__ u32x2 pack4(f32x4 v) {
  u32x2 p;
  p.x = (unsigned)f2bf(v.x) | ((unsigned)f2bf(v.y) << 16);
  p.y = (unsigned)f2bf(v.z) | ((unsigned)f2bf(v.w) << 16);
  return p;
}

__device__ __forceinline__ f32x4 mfma16(bf16x8 a, bf16x8 b, f32x4 c) {
  return __builtin_amdgcn_mfma_f32_16x16x32_bf16(a, b, c, 0, 0, 0);
}

__device__ __forceinline__ bf16x8 as_bf(u32x4 u) {
  return __builtin_bit_cast(bf16x8, u);
}

// packed bf16 convert: dword = {bf16(lo) | bf16(hi)<<16}
__device__ __forceinline__ unsigned cvtpk(float lo, float hi) {
  unsigned d;
  asm("v_cvt_pk_bf16_f32 %0, %1, %2" : "=v"(d) : "v"(lo), "v"(hi));
  return d;
}

typedef __attribute__((address_space(3))) const unsigned short* lds_cptr;
typedef __attribute__((address_space(1))) const void* gvp;
typedef __attribute__((address_space(3))) void* svp;

// ds_read_b64_tr_b16: lane fetches 8B at its own addr (subtile base + (lane&15)*8);
// HW transposes within 16-lane groups: lane c elem j holds tile[j][c] of [4][16] bf16.
__device__ __forceinline__ s16x4 tr16(const void* p) {
  s16x4 r;
  lds_cptr lp = (lds_cptr)p;
  asm volatile("ds_read_b64_tr_b16 %0, %1" : "=v"(r) : "v"(lp));
  return r;
}

// async global->LDS, 16B/lane; LDS dest = wave-uniform base + lane*16 (linear).
__device__ __forceinline__ void gll16(const void* g, void* l) {
  __builtin_amdgcn_global_load_lds((gvp)g, (svp)l, 16, 0, 0);
}

// ---------------- Kernel 0: f32 -> bf16 convert (x, Ww ONLY) ----------------
__global__ __launch_bounds__(256) void tobf16(const float* __restrict__ x,
                                              const float* __restrict__ ww,
                                              unsigned short* __restrict__ xB,
                                              unsigned short* __restrict__ wwB) {
  long i8 = (long)blockIdx.x * 256 + threadIdx.x;
  if (i8 < 1048576L) {
    f32x4 a = *(const f32x4*)(x + i8 * 8);
    f32x4 c = *(const f32x4*)(x + i8 * 8 + 4);
    u32x2 p0 = pack4(a), p1 = pack4(c);
    u32x4 o;
    o.x = p0.x; o.y = p0.y; o.z = p1.x; o.w = p1.y;
    *(u32x4*)(xB + i8 * 8) = o;
  } else {
    long k = i8 - 1048576L;   // 0..36863
    f32x4 a = *(const f32x4*)(ww + k * 8);
    f32x4 c = *(const f32x4*)(ww + k * 8 + 4);
    u32x2 p0 = pack4(a), p1 = pack4(c);
    u32x4 o;
    o.x = p0.x; o.y = p0.y; o.z = p1.x; o.w = p1.y;
    *(u32x4*)(wwB + k * 8) = o;
  }
}

// ---------------- Kernel 1: q = (xB @ WwB^T + b) * 0.125  +  wdkv permute ----------
// GEMM blocks 0..383: m0 = (bid&127)*64, c0 = (bid>>7)*96 -- the 3 col-blocks of one
// m0 get ids {g, g+128, g+256}, all == g (mod 8) -> SAME XCD -> xB re-reads become
// L2 hits (round-19: the qproj dispatch is HBM-saturated; traffic cut = time cut).
// Blocks 384..1535: wdkv f32 -> wdkvT tiled-image permute (consumed only by attn).
__global__ __launch_bounds__(256, 4) void qproj(const unsigned short* __restrict__ xB,
                                                const unsigned short* __restrict__ wwB,
                                                const float* __restrict__ Wb,
                                                unsigned short* __restrict__ q,
                                                const float* __restrict__ wdkv,
                                                unsigned short* __restrict__ wdkvT) {
  __shared__ unsigned short xl[2][64 * 64];
  __shared__ unsigned short wl[2][96 * 64];
  if (blockIdx.x >= 384) {
    // ---- wdkv permute block ----
    long k = (long)(blockIdx.x - 384) * 256 + threadIdx.x;  // 0..294911
    int b = (int)(k / 73728);
    int rem = (int)(k % 73728);
    int srow = rem / 36;
    int l8 = rem - srow * 36;
    int st = srow >> 6;
    int s = srow & 63;
    int j = (l8 >> 1) * 2 + (s >> 5);
    int lane = ((s & 31) >> 2) * 8 + (s & 3) * 2 + (l8 & 1);
    f32x4 a = *(const f32x4*)(wdkv + k * 8);
    f32x4 c = *(const f32x4*)(wdkv + k * 8 + 4);
    u32x2 p0 = pack4(a), p1 = pack4(c);
    u32x4 o;
    o.x = p0.x; o.y = p0.y; o.z = p1.x; o.w = p1.y;
    *(u32x4*)((char*)wdkvT + (((long)(b * 32 + st) * 36 + j) << 10) + lane * 16) = o;
    return;
  }
  const int tid = threadIdx.x;
  const int lane = tid & 63;
  const int w = tid >> 6;
  const int g = lane >> 4;
  const int r = lane & 15;
  const int m0 = (blockIdx.x & 127) * 64;
  const int c0 = (blockIdx.x >> 7) * 96;

  const int o_i = (lane >> 3) * 2048 + (((lane & 7) * 16) ^ ((lane >> 3) << 4));

  f32x4 acc[6];
#pragma unroll
  for (int i = 0; i < 6; ++i) acc[i] = (f32x4)0.0f;

  const char* xsrc = (const char*)xB + (long)m0 * 2048;
  const char* wsrc = (const char*)wwB + (long)c0 * 2048;

#define QPROJ_ISSUE(kb2, cb)                                            \
  {                                                                     \
    char* xd = (char*)&xl[cb][0];                                       \
    char* wd = (char*)&wl[cb][0];                                       \
    _Pragma("unroll") for (int jj = 0; jj < 2; ++jj) {                  \
      int j = 2 * w + jj;                                               \
      gll16(xsrc + (long)j * 16384 + (kb2) + o_i, xd + j * 1024);       \
    }                                                                   \
    _Pragma("unroll") for (int jj = 0; jj < 3; ++jj) {                  \
      int j = 3 * w + jj;                                               \
      gll16(wsrc + (long)j * 16384 + (kb2) + o_i, wd + j * 1024);       \
    }                                                                   \
  }

  QPROJ_ISSUE(0, 0);
  for (int ks = 0; ks < 16; ++ks) {
    const int cb = ks & 1;
    if (ks < 15) {
      QPROJ_ISSUE((ks + 1) * 128, cb ^ 1);
      asm volatile("s_waitcnt vmcnt(5)" ::: "memory");
    } else {
      asm volatile("s_waitcnt vmcnt(0)" ::: "memory");
    }
    __builtin_amdgcn_s_barrier();
    __builtin_amdgcn_sched_barrier(0);
    const char* xlb = (const char*)&xl[cb][0];
    const char* wlb = (const char*)&wl[cb][0];
#pragma unroll
    for (int kc = 0; kc < 2; ++kc) {
      int koff = kc * 64 + g * 16;
      bf16x8 a = as_bf(*(const u32x4*)(xlb + (16 * w + r) * 128 + (koff ^ ((r & 7) << 4))));
#pragma unroll
      for (int nf = 0; nf < 6; ++nf) {
        int l = nf * 16 + r;
        bf16x8 bb = as_bf(*(const u32x4*)(wlb + l * 128 + (koff ^ ((l & 7) << 4))));
        acc[nf] = mfma16(a, bb, acc[nf]);
      }
    }
    __builtin_amdgcn_sched_barrier(0);
    __builtin_amdgcn_s_barrier();
    __builtin_amdgcn_sched_barrier(0);
  }
  const int rowb = m0 + 16 * w + 4 * g;
#pragma unroll
  for (int nf = 0; nf < 6; ++nf) {
    int col = c0 + nf * 16 + r;
    float bias = Wb[col];
#pragma unroll
    for (int e = 0; e < 4; ++e) {
      float qv = (acc[nf][e] + bias) * 0.125f;
      q[(long)(rowb + e) * LL + col] = f2bf(qv);
    }
  }
}

// ---------------- Kernel 2: causal flash attn, swapped QK^T, 1 barrier/step --------
// Round-15 form (best measured): swapped QK^T, in-register P exchange, PV 2-deep
// counted-lgkmcnt cluster pipeline. CH=5 -> 244 blocks <= 256 CUs.
__global__ __launch_bounds__(512, 2) void attn(const unsigned short* __restrict__ wdkvT,
                                               const unsigned short* __restrict__ q,
                                               float* __restrict__ out,
                                               char* __restrict__ partial,
                                               int CH, int SPB) {
  __shared__ unsigned short Vt[2][18 * 16 * 64];  // 2 x 36864 B, subtiled tr16 layout
  const int tid = threadIdx.x;
  const int lane = tid & 63;
  const int w = tid >> 6;
  const int g = lane >> 4;
  const int r = lane & 15;

  const int bid = blockIdx.x;
  const int b = bid / SPB;
  int rem = bid - b * SPB;
  int t = 0, base = 0, nch = 1;
  for (;;) {
    nch = (2 * t + 2 + CH - 1) / CH;
    if (rem < base + nch) break;
    base += nch;
    ++t;
  }
  const int c = rem - base;
  const bool direct = (nch == 1);
  const int q0 = t * 128;
  const int st0 = c * CH;
  const int st1 = min((c + 1) * CH, 2 * t + 2);

  char* vt0 = (char*)&Vt[0][0];
  char* vt1 = (char*)&Vt[1][0];

  const char* wsrcT = (const char*)wdkvT + (long)b * 32 * 36864;

  bf16x8 qf[9];
  {
    const long qrow = (long)b * TT + q0 + 16 * w + r;
#pragma unroll
    for (int kc = 0; kc < 9; ++kc)
      qf[kc] = as_bf(*(const u32x4*)(q + qrow * LL + kc * 32 + 8 * g));
  }

  f32x4 o[18];
#pragma unroll
  for (int i = 0; i < 18; ++i) o[i] = (f32x4)0.0f;
  float mr = -1e30f, lr = 0.0f;

#define ATTN_ISSUE(st_, dst_)                                          \
  {                                                                    \
    const char* srcT = wsrcT + (long)(st_) * 36864;                    \
    _Pragma("unroll") for (int jj = 0; jj < 5; ++jj) {                 \
      int j = w + 8 * jj;                                              \
      if (j < 36) gll16(srcT + j * 1024 + lane * 16, (dst_) + j * 1024);\
    }                                                                  \
  }

  const int rq = q0 + 16 * w + r;
  const int srcA = r + 32 * (g & 1);
  const int srcB = srcA + 16;
  const bool gsel = (g & 2) != 0;

  ATTN_ISSUE(st0, vt0);
  for (int st = st0; st < st1; ++st) {
    const int sb = st * 64;
    const int cbi = (st - st0) & 1;
    char* vtb = cbi ? vt1 : vt0;
    char* vtn = cbi ? vt0 : vt1;
    asm volatile("s_waitcnt vmcnt(0)" ::: "memory");
    __builtin_amdgcn_s_barrier();
    __builtin_amdgcn_sched_barrier(0);
    if (st + 1 < st1) ATTN_ISSUE(st + 1, vtn);
    // ---- swapped QK^T: sa[sf][e] = S[s = sb+16sf+4g+e][q = rq] ----
    f32x4 sa[4];
#pragma unroll
    for (int i = 0; i < 4; ++i) sa[i] = (f32x4)0.0f;
    __builtin_amdgcn_s_setprio(1);
#pragma unroll
    for (int kc = 0; kc < 9; ++kc) {
      const int lblk2048 = (2 * kc + (g >> 1)) * 2048;
      const int lrem16 = (g & 1) * 16;
#pragma unroll
      for (int sf = 0; sf < 4; ++sf) {
        bf16x8 vv = as_bf(*(const u32x4*)(vtb + lblk2048 + (4 * sf + (r >> 2)) * 128 + (r & 3) * 32 + lrem16));
        sa[sf] = mfma16(vv, qf[kc], sa[sf]);
      }
    }
    __builtin_amdgcn_s_setprio(0);
    // ---- mask + per-lane rowmax ----
    float tm = -1e30f;
#pragma unroll
    for (int sf = 0; sf < 4; ++sf)
#pragma unroll
      for (int e = 0; e < 4; ++e) {
        int sg = sb + 16 * sf + 4 * g + e;
        if (sg > rq) sa[sf][e] = -1e30f;
        tm = fmaxf(tm, sa[sf][e]);
      }
    tm = fmaxf(tm, __shfl_xor(tm, 16));
    tm = fmaxf(tm, __shfl_xor(tm, 32));
    const float mn = fmaxf(mr, tm);
    const float al = __expf(mr - mn);
    mr = mn;
    float rs = 0.0f;
#pragma unroll
    for (int sf = 0; sf < 4; ++sf)
#pragma unroll
      for (int e = 0; e < 4; ++e) {
        float pv = __expf(sa[sf][e] - mn);
        sa[sf][e] = pv;
        rs += pv;
      }
    rs += __shfl_xor(rs, 16);
    rs += __shfl_xor(rs, 32);
    lr = lr * al + rs;
    float alr[4];
#pragma unroll
    for (int e = 0; e < 4; ++e) alr[e] = __shfl(al, 4 * g + e);
#pragma unroll
    for (int nf = 0; nf < 18; ++nf)
#pragma unroll
      for (int e = 0; e < 4; ++e) o[nf][e] *= alr[e];
    // ---- pack P to bf16 pairs ----
    unsigned pk[4][2];
#pragma unroll
    for (int sf = 0; sf < 4; ++sf) {
      pk[sf][0] = cvtpk(sa[sf][0], sa[sf][1]);
      pk[sf][1] = cvtpk(sa[sf][2], sa[sf][3]);
    }
    // ---- precompute BOTH PV A-fragments ----
    bf16x8 paK0, paK1;
#pragma unroll
    for (int kc2 = 0; kc2 < 2; ++kc2) {
      int xa0 = __shfl((int)pk[2 * kc2 + 0][0], srcA);
      int xb0 = __shfl((int)pk[2 * kc2 + 1][0], srcA);
      int xa1 = __shfl((int)pk[2 * kc2 + 0][1], srcA);
      int xb1 = __shfl((int)pk[2 * kc2 + 1][1], srcA);
      int ya0 = __shfl((int)pk[2 * kc2 + 0][0], srcB);
      int yb0 = __shfl((int)pk[2 * kc2 + 1][0], srcB);
      int ya1 = __shfl((int)pk[2 * kc2 + 0][1], srcB);
      int yb1 = __shfl((int)pk[2 * kc2 + 1][1], srcB);
      u32x4 pd;
      pd.x = (unsigned)(gsel ? xb0 : xa0);
      pd.y = (unsigned)(gsel ? xb1 : xa1);
      pd.z = (unsigned)(gsel ? yb0 : ya0);
      pd.w = (unsigned)(gsel ? yb1 : ya1);
      if (kc2 == 0) paK0 = as_bf(pd); else paK1 = as_bf(pd);
    }
    asm volatile("" : "+v"(paK0), "+v"(paK1));
    // drain shuffle bpermutes so the counted FIFO below holds only tr16s
    asm volatile("s_waitcnt lgkmcnt(0)" ::: "memory");
    __builtin_amdgcn_sched_barrier(0);
    // ---- PV: 12 clusters (kc2 x gg), 2-deep counted-lgkmcnt pipeline ----
    s16x4 tq[2][6];
#define PV_CL(c_, sl_)                                                      \
    {                                                                       \
      const int kc2_ = (c_) / 6, gg_ = (c_) % 6;                            \
      const char* ap = vtb + kc2_ * 1024 + g * 256 + r * 8;                 \
      _Pragma("unroll") for (int i = 0; i < 3; ++i) {                       \
        int nf_ = gg_ * 3 + i;                                              \
        tq[sl_][2 * i] = tr16(ap + nf_ * 2048);                             \
        tq[sl_][2 * i + 1] = tr16(ap + nf_ * 2048 + 128);                   \
      }                                                                     \
    }
    __builtin_amdgcn_s_setprio(1);
    PV_CL(0, 0);
#pragma unroll
    for (int c2 = 0; c2 < 12; ++c2) {
      if (c2 < 11) {
        PV_CL(c2 + 1, (c2 + 1) & 1);
        asm volatile("s_waitcnt lgkmcnt(6)" ::: "memory");
      } else {
        asm volatile("s_waitcnt lgkmcnt(0)" ::: "memory");
      }
      __builtin_amdgcn_sched_barrier(0);
      const int gg_ = c2 % 6;
      const bf16x8 pa = (c2 < 6) ? paK0 : paK1;
#pragma unroll
      for (int i = 0; i < 3; ++i) {
        int nf = gg_ * 3 + i;
        s16x4 t0 = tq[c2 & 1][2 * i], t1 = tq[c2 & 1][2 * i + 1];
        bf16x8 bb;
        bb[0] = t0[0]; bb[1] = t0[1]; bb[2] = t0[2]; bb[3] = t0[3];
        bb[4] = t1[0]; bb[5] = t1[1]; bb[6] = t1[2]; bb[7] = t1[3];
        o[nf] = mfma16(pa, bb, o[nf]);
      }
    }
    __builtin_amdgcn_s_setprio(0);
  }
  // ---- epilogue ----
  if (direct) {
    float lrr[4];
#pragma unroll
    for (int e = 0; e < 4; ++e) lrr[e] = __shfl(lr, 4 * g + e);
    const long trow = (long)b * TT + q0 + 16 * w + 4 * g;
#pragma unroll
    for (int nf = 0; nf < 18; ++nf) {
      int col = 16 * nf + r;
#pragma unroll
      for (int e = 0; e < 4; ++e)
        out[(trow + e) * LL + col] = o[nf][e] / lrr[e];
    }
  } else {
    char* sp = partial + (size_t)(b * SPB + rem) * SLOTB2;
    if (g == 0) {
      ((float*)sp)[16 * w + r] = mr;
      ((float*)(sp + 512))[16 * w + r] = lr;
    }
#pragma unroll
    for (int p = 0; p < 9; ++p) {
      u32x2 a0 = pack4(o[2 * p]);
      u32x2 a1 = pack4(o[2 * p + 1]);
      u32x4 v;
      v.x = a0.x; v.y = a0.y; v.z = a1.x; v.w = a1.y;
      *(u32x4*)(sp + 1024 + p * 8192 + tid * 16) = v;
    }
  }
}

// ---------------- Kernel 3: combine partials in FRAGMENT space ----------------
__global__ __launch_bounds__(512) void reduce_k(const char* __restrict__ partial,
                                                float* __restrict__ out,
                                                int CH, int SPB, int NMT) {
  const int bid = blockIdx.x;
  const int nfl = bid % 9;
  const int rest = bid / 9;
  const int b = rest / NMT;
  int idx = rest % NMT;
  int t = 0, base = 0, nch = 1;
  for (;;) {
    nch = (2 * t + 2 + CH - 1) / CH;
    if (nch > 1) {
      if (idx == 0) break;
      --idx;
    }
    base += nch;
    ++t;
  }
  const char* sp0 = partial + (size_t)(b * SPB + base) * SLOTB2;

  const int tid = threadIdx.x;
  const int w = tid >> 6;
  const int g = (tid & 63) >> 4;
  const int r = tid & 15;
  const int row0 = 16 * w + 4 * g;

  float M[4], Lx[4], acc[8];
#pragma unroll
  for (int e = 0; e < 4; ++e) { M[e] = -1e30f; Lx[e] = 0.0f; }
#pragma unroll
  for (int k = 0; k < 8; ++k) acc[k] = 0.0f;

  for (int i = 0; i < nch; ++i) {
    const char* sp = sp0 + (size_t)i * SLOTB2;
    const float* mv = (const float*)sp;
    const float* lv = (const float*)(sp + 512);
    u32x4 v = *(const u32x4*)(sp + 1024 + nfl * 8192 + tid * 16);
    const unsigned short* pu = (const unsigned short*)&v;
    float fo[4], fi[4];
#pragma unroll
    for (int e = 0; e < 4; ++e) {
      float mi = mv[row0 + e];
      float mn = fmaxf(M[e], mi);
      fo[e] = __expf(M[e] - mn);
      fi[e] = __expf(mi - mn);
      Lx[e] = Lx[e] * fo[e] + fi[e] * lv[row0 + e];
      M[e] = mn;
    }
#pragma unroll
    for (int k = 0; k < 8; ++k)
      acc[k] = acc[k] * fo[k & 3] + fi[k & 3] * __uint_as_float((unsigned)pu[k] << 16);
  }
#pragma unroll
  for (int k = 0; k < 8; ++k) {
    int row = row0 + (k & 3);
    int col = 16 * (2 * nfl + (k >> 2)) + r;
    out[((size_t)b * TT + t * 128 + row) * LL + col] = acc[k] / Lx[k & 3];
  }
}

extern "C" void kernel_launch(void* const* d_in, const int* in_sizes, int n_in,
                              void* d_out, int out_size, void* d_ws, size_t ws_size,
                              hipStream_t stream) {
  const float* x = (const float*)d_in[0];
  const float* Wdkv = (const float*)d_in[1];
  const float* Ww = (const float*)d_in[2];
  const float* Wb = (const float*)d_in[3];
  float* outp = (float*)d_out;

  char* ws = (char*)d_ws;
  unsigned short* qB = (unsigned short*)ws;                  // 4,718,592 B
  unsigned short* xB = (unsigned short*)(ws + 4718592);      // 16,777,216 B
  unsigned short* wdkvT = (unsigned short*)(ws + 21495808);  // 4,718,592 B (tiled image)
  unsigned short* wwB = (unsigned short*)(ws + 26214400);    // 589,824 B
  char* partialB = ws + 26804224;

  // CH ladder: CH=5 -> SPB=61 -> 244 blocks <= 256 CUs (1 block/CU; round-11 lesson).
  int CH = 32, SPB = 16;
  const int chs[4] = {5, 8, 16, 32};
  for (int ci = 0; ci < 4; ++ci) {
    int ch = chs[ci];
    int spb = 0;
    for (int t = 0; t < 16; ++t) spb += (2 * t + 2 + ch - 1) / ch;
    if (26804224 + (size_t)4 * spb * SLOTB2 <= ws_size) { CH = ch; SPB = spb; break; }
  }
  int NMT = 0;
  for (int t = 0; t < 16; ++t)
    if ((2 * t + 2 + CH - 1) / CH > 1) ++NMT;

  tobf16<<<4240, 256, 0, stream>>>(x, Ww, xB, wwB);
  qproj<<<1536, 256, 0, stream>>>(xB, wwB, Wb, qB, Wdkv, wdkvT);
  attn<<<4 * SPB, 512, 0, stream>>>(wdkvT, qB, outp, partialB, CH, SPB);
  if (NMT > 0) reduce_k<<<4 * NMT * 9, 512, 0, stream>>>(partialB, outp, CH, SPB, NMT);
}